// Round 10
// baseline (124.868 us; speedup 1.0000x reference)
//
#include <hip/hip_runtime.h>
#include <stdint.h>

// ---------------------------------------------------------------------------
// LinearBlock: out[b, p*8+o] = clip((sum_{q,i} Wq[p,q,o,i]*xq[b,q*8+i])^2, 0, 6)
// Exact int8 path (9x verified):
//   xq = xu/255, wq = wi*2/127, dot=(sum xu*wi)*2/(255*127); zero-point via
//   xs=xu-128 and +128*rowsum[n].
//
// Round 10: round-9 geometry, ZERO inline asm. 256x256, BK=128, 8 waves
// (2Mx4N), 32x32x32 MFMA, double-buffered 128 KB LDS, one __syncthreads per
// K-tile, plain-HIP loads and MFMA loops -- the compiler schedules reads vs
// MFMAs with its own counted lgkmcnt (m97 style). Tests the hypothesis that
// rounds 2-9's constant ~30% MfmaUtil was caused by hand s_waitcnt +
// sched_barrier(0) pinning (common-mistake #5 / m141).
// ---------------------------------------------------------------------------

typedef int i32x4  __attribute__((ext_vector_type(4)));
typedef int i32x16 __attribute__((ext_vector_type(16)));

#define B_DIM   16384
#define IN_DIM  2048
#define OUT_DIM 2048

#define BM 256
#define BN 256
#define BK 128
#define KTILES (IN_DIM / BK)   // 16
#define ATILE  (BM * BK)       // 32768 bytes
#define BUFB   (2 * ATILE)     // 65536 bytes (A half + B half)

__device__ __forceinline__ void async16(const void* g, void* l) {
    __builtin_amdgcn_global_load_lds(
        (const __attribute__((address_space(1))) void*)g,
        (__attribute__((address_space(3))) void*)l, 16, 0, 0);
}

// --- quantize x: float [B,IN] -> int8 (value-128) [B,IN], 16 elems/thread ---
__global__ __launch_bounds__(256) void quant_x_kernel(const float* __restrict__ x,
                                                      int8_t* __restrict__ xq) {
    int i = blockIdx.x * 256 + threadIdx.x;
    const float4* xv = (const float4*)x + (size_t)i * 4;
    union { int8_t c[16]; i32x4 v; } u;
#pragma unroll
    for (int j = 0; j < 4; ++j) {
        float4 v = xv[j];
        float f[4] = {v.x, v.y, v.z, v.w};
#pragma unroll
        for (int e = 0; e < 4; ++e) {
            float c = fminf(fmaxf(f[e], 0.0f), 1.0f);
            int q = (int)rintf(c * 255.0f) - 128;
            u.c[j * 4 + e] = (int8_t)q;
        }
    }
    *((i32x4*)xq + i) = u.v;
}

// --- quantize + relayout weight: [P=256,Q=256,8,8] f32 -> [2048][2048] int8
__global__ __launch_bounds__(256) void quant_w_kernel(const float* __restrict__ w,
                                                      int8_t* __restrict__ wq,
                                                      int* __restrict__ rowsum) {
    int p = blockIdx.x;
    int t = threadIdx.x;
    const float* wp = w + (size_t)p * 16384;
    int n = p * 8 + (t & 7);
    int lsum = 0;
#pragma unroll
    for (int s = 0; s < 8; ++s) {
        int g = t + s * 256;
        float4 v0 = *(const float4*)(wp + g * 8);
        float4 v1 = *(const float4*)(wp + g * 8 + 4);
        float f[8] = {v0.x, v0.y, v0.z, v0.w, v1.x, v1.y, v1.z, v1.w};
        union { int8_t c[8]; long long ll; } u;
#pragma unroll
        for (int e = 0; e < 8; ++e) {
            float c = fminf(fmaxf(f[e], -2.0f), 2.0f);
            int q = (int)rintf(c * 63.5f);
            u.c[e] = (int8_t)q;
            lsum += q;
        }
        int kg = g >> 3;
        *(long long*)(wq + (size_t)n * 2048 + kg * 8) = u.ll;
    }
    atomicAdd(&rowsum[n], lsum);
}

#define LD(p) (*(const i32x4*)(p))
#define MFMA32(a, b, c) __builtin_amdgcn_mfma_i32_32x32x32_i8(a, b, c, 0, 0, 0)

// --- int8 GEMM: 256x256, BK=128, 8 waves, 32x32x32, compiler-scheduled ---
__global__ __launch_bounds__(512, 2) void gemm_i8_kernel(const int8_t* __restrict__ A,
                                                         const int8_t* __restrict__ W,
                                                         const int* __restrict__ rowsum,
                                                         float* __restrict__ out) {
    extern __shared__ int8_t lds[];   // 2 * 64 KB

    // XCD-aware swizzle: 512 wgs, 8 XCDs, 64 contiguous tiles per XCD
    int bid = blockIdx.x;
    int wg = (bid & 7) * 64 + (bid >> 3);
    int tm = wg >> 3;
    int tn = wg & 7;
    int browG = tm * BM;
    int bcolG = tn * BN;

    int tid  = threadIdx.x;
    int lane = tid & 63;
    int wv   = tid >> 6;
    int wr = wv >> 2, wc = wv & 3;    // 2x4 waves, wave tile 128x64
    int l31 = lane & 31;
    int hi  = lane >> 5;              // 0..1

    // staging (verified r5/r7/r9): thread covers rows (tid>>3)+s*64, chunk
    // col tid&7; LDS chunk (r,c) holds global chunk (r, c ^ ((r>>1)&7)).
    int csw = (tid & 7) ^ ((tid >> 4) & 7);
    const int8_t* gA = A + (size_t)(browG + (tid >> 3)) * IN_DIM + csw * 16;
    const int8_t* gB = W + (size_t)(bcolG + (tid >> 3)) * IN_DIM + csw * 16;
    const int t16 = tid * 16;

    // ds_read (verified r9): A row = wr*128 + m*32 + l31; B row = wc*64 +
    // n*32 + l31; k-chunk kc = 2*ks + hi, swizzled kc ^ ((l31>>1)&7).
    const int xsw = (l31 >> 1) & 7;
    int kof[4];
#pragma unroll
    for (int ks = 0; ks < 4; ++ks)
        kof[ks] = (((2 * ks + hi) ^ xsw) << 4);
    const int arowO = (wr * 128 + l31) * BK;   // + m*4096
    const int browO = (wc * 64 + l31) * BK;    // + n*4096

    i32x16 acc[4][2];
#pragma unroll
    for (int m = 0; m < 4; ++m)
#pragma unroll
        for (int n = 0; n < 2; ++n)
            acc[m][n] = (i32x16){0, 0, 0, 0, 0, 0, 0, 0, 0, 0, 0, 0, 0, 0, 0, 0};

    // ---- prologue: stage tile 0 into buf0 ----
    async16(gA, lds + t16);
    async16(gA + 131072, lds + 8192 + t16);
    async16(gA + 262144, lds + 16384 + t16);
    async16(gA + 393216, lds + 24576 + t16);
    async16(gB, lds + ATILE + t16);
    async16(gB + 131072, lds + ATILE + 8192 + t16);
    async16(gB + 262144, lds + ATILE + 16384 + t16);
    async16(gB + 393216, lds + ATILE + 24576 + t16);
    __syncthreads();

    // ---- main loop: one __syncthreads per K-tile, compiler-scheduled ----
#pragma unroll 1
    for (int kt = 0; kt < KTILES; ++kt) {
        const int cur = kt & 1;
        const int8_t* la = lds + cur * BUFB;
        const int8_t* lb = la + ATILE;

        if (kt < KTILES - 1) {
            int8_t* dst = lds + (cur ^ 1) * BUFB;
            const int kb = (kt + 1) * BK;
            async16(gA + kb, dst + t16);
            async16(gA + 131072 + kb, dst + 8192 + t16);
            async16(gA + 262144 + kb, dst + 16384 + t16);
            async16(gA + 393216 + kb, dst + 24576 + t16);
            async16(gB + kb, dst + ATILE + t16);
            async16(gB + 131072 + kb, dst + ATILE + 8192 + t16);
            async16(gB + 262144 + kb, dst + ATILE + 16384 + t16);
            async16(gB + 393216 + kb, dst + ATILE + 24576 + t16);
        }

#pragma unroll
        for (int ks = 0; ks < 4; ++ks) {
            i32x4 a0 = LD(la + arowO + kof[ks]);
            i32x4 a1 = LD(la + arowO + 4096 + kof[ks]);
            i32x4 a2 = LD(la + arowO + 8192 + kof[ks]);
            i32x4 a3 = LD(la + arowO + 12288 + kof[ks]);
            i32x4 b0 = LD(lb + browO + kof[ks]);
            i32x4 b1 = LD(lb + browO + 4096 + kof[ks]);
            acc[0][0] = MFMA32(a0, b0, acc[0][0]);
            acc[0][1] = MFMA32(a0, b1, acc[0][1]);
            acc[1][0] = MFMA32(a1, b0, acc[1][0]);
            acc[1][1] = MFMA32(a1, b1, acc[1][1]);
            acc[2][0] = MFMA32(a2, b0, acc[2][0]);
            acc[2][1] = MFMA32(a2, b1, acc[2][1]);
            acc[3][0] = MFMA32(a3, b0, acc[3][0]);
            acc[3][1] = MFMA32(a3, b1, acc[3][1]);
        }
        __syncthreads();
    }

    // ---- epilogue: zero-point, scale, photodetect square, ReLUN(6) ----
    // C/D 32x32 map: col = lane&31, row = (reg&3) + 8*(reg>>2) + 4*(lane>>5)
    const float scale = (float)(2.0 / 32385.0);
#pragma unroll
    for (int n = 0; n < 2; ++n) {
        int col = bcolG + wc * 64 + n * 32 + l31;
        int rs128 = rowsum[col] << 7;
#pragma unroll
        for (int m = 0; m < 4; ++m) {
            int rb = browG + wr * 128 + m * 32 + hi * 4;
#pragma unroll
            for (int r = 0; r < 16; ++r) {
                int row = rb + (r & 3) + 8 * (r >> 2);
                float f = (float)(acc[m][n][r] + rs128) * scale;
                f = f * f;
                f = fminf(f, 6.0f);
                out[(size_t)row * OUT_DIM + col] = f;
            }
        }
    }
}

extern "C" void kernel_launch(void* const* d_in, const int* in_sizes, int n_in,
                              void* d_out, int out_size, void* d_ws, size_t ws_size,
                              hipStream_t stream) {
    const float* x  = (const float*)d_in[0];   // [16384, 2048] f32
    const float* wt = (const float*)d_in[1];   // [256, 256, 8, 8] f32
    float* out = (float*)d_out;                // [16384, 2048] f32

    char* ws = (char*)d_ws;
    int8_t* xq = (int8_t*)ws;                                   // 32 MB
    int8_t* wq = (int8_t*)(ws + (size_t)B_DIM * IN_DIM);        // 4 MB
    int*    rowsum = (int*)(ws + (size_t)B_DIM * IN_DIM
                               + (size_t)OUT_DIM * IN_DIM);     // 8 KB

    hipMemsetAsync(rowsum, 0, OUT_DIM * sizeof(int), stream);
    quant_x_kernel<<<(B_DIM * IN_DIM / 16) / 256, 256, 0, stream>>>(x, xq);
    quant_w_kernel<<<256, 256, 0, stream>>>(wt, wq, rowsum);
    gemm_i8_kernel<<<(B_DIM / BM) * (OUT_DIM / BN), 512, 2 * BUFB, stream>>>(xq, wq, rowsum, out);
}